// Round 9
// baseline (124.539 us; speedup 1.0000x reference)
//
#include <hip/hip_runtime.h>
#include <math.h>

// ws layout (floats):
//   [0..3199]    cT[25][32][4] : cT[c][l][u] = coef[l][4c+u]; coef[l][n] = w[n]*(mk[l,n]-bw[l])
//   [3200..3299] wT[100]       : w[n]
//   [3300..3591] sm[292]       : scalars/small matrices (SM_* offsets)
#define WS_CT 0
#define WS_WT 3200
#define WS_SM 3300
#define WS_TOT 3592            // = 898 float4

#define SM_WSUM 0
#define SM_RWS  1
#define SM_Q00  2
#define SM_Z2   4
#define SM_BS   16
#define SM_W    48
#define SM_G    148
#define SM_GV   248
#define SM_BW   260

// kernel-2 LDS layout (floats); first WS_TOT copied linearly from ws
#define LS_SF   3600           // [4][96]  centered F
#define LS_QL   3984           // [4][57]  Q upper-tri (stride 57: conflict-free)
#define LS_AX   4212           // [4][16]  yw[3] @0, G3[9] @3
#define LS_TOT  4276

__host__ __device__ constexpr int TRI(int p,int q){ return p*10-(p*(p+1))/2+q; } // p<=q
__host__ __device__ constexpr int SIDX(int a,int b){ return (a<=b)?TRI(a,b):TRI(b,a); }
__host__ __device__ constexpr int LTRI(int i,int j){ return i*(i+1)/2+j; }       // j<=i

template<int CTRL>
__device__ __forceinline__ float dpp_add(float v){
  int s = __builtin_amdgcn_mov_dpp(__float_as_int(v), CTRL, 0xF, 0xF, true);
  return v + __int_as_float(s);
}
// 32-lane group sum: 4 DPP stages within 16 + xor-16 swizzle (per-32-lane groups)
__device__ __forceinline__ float gsum32(float v){
  v = dpp_add<0xB1>(v);    // quad xor1
  v = dpp_add<0x4E>(v);    // quad xor2
  v = dpp_add<0x141>(v);   // row_half_mirror
  v = dpp_add<0x140>(v);   // row_mirror (16-lane)
  v += __int_as_float(__builtin_amdgcn_ds_swizzle(__float_as_int(v), 0x401F)); // xor 16
  return v;
}

// =================== kernel 1: precompute table into ws (1 block x 256) ===================
__global__ __launch_bounds__(256) void pace_pre(const float* __restrict__ w,
                                                const float* __restrict__ mk,
                                                float* __restrict__ ws){
  __shared__ __attribute__((aligned(16))) float s_mb[3000];
  __shared__ __attribute__((aligned(16))) float s_w[104], s_sw[104];
  __shared__ float s_bw[32];
  __shared__ float s_C[100], s_Hi[100], s_G[100], s_T[100];
  __shared__ float s_gv[12], s_Ht[12], s_z[12];
  const int tid = threadIdx.x;
  const int lane = tid & 63;

  for (int i=tid;i<3000;i+=256) s_mb[i]=mk[i];
  for (int i=tid;i<100;i+=256){ float x=w[i]; s_w[i]=x; s_sw[i]=sqrtf(x); }
  __syncthreads();

  float av = s_w[lane] + ((lane<36)? s_w[lane+64] : 0.f);
  #pragma unroll
  for (int m=32;m;m>>=1) av += __shfl_xor(av,m);
  const float wsum = av;
  const float rws  = 1.0f/av;

  if (tid<30){
    const float4* p=(const float4*)&s_mb[tid*100];
    const float4* q=(const float4*)&s_w[0];
    float acc=0;
    #pragma unroll 5
    for (int j=0;j<25;j++){ float4 x=p[j], yv=q[j];
      acc=fmaf(x.x,yv.x,acc); acc=fmaf(x.y,yv.y,acc);
      acc=fmaf(x.z,yv.z,acc); acc=fmaf(x.w,yv.w,acc); }
    s_bw[tid]=acc*rws;
  }
  __syncthreads();
  for (int i=tid;i<3000;i+=256){ int r=i/100, n=i-r*100; s_mb[i]=s_sw[n]*(s_mb[i]-s_bw[r]); }
  __syncthreads();
  if (tid<100){   // C = barB^T barB
    int k=tid/10, k2=tid-10*(tid/10);
    const float4* p1=(const float4*)&s_mb[k*300];
    const float4* p2=(const float4*)&s_mb[k2*300];
    float acc=0;
    #pragma unroll 5
    for (int j=0;j<75;j++){ float4 x=p1[j], yv=p2[j];
      acc=fmaf(x.x,yv.x,acc); acc=fmaf(x.y,yv.y,acc);
      acc=fmaf(x.z,yv.z,acc); acc=fmaf(x.w,yv.w,acc); }
    s_C[tid]=acc;
  }
  __syncthreads();
  if (tid<64){    // Gauss-Jordan inversion of 2(C+I), wave0 lanes 0..9 own rows
    float R[20];
    {
      int row=(tid<10)? tid : 0;
      #pragma unroll
      for (int c=0;c<10;c++) R[c]=2.0f*(s_C[row*10+c]+(c==row?1.0f:0.0f));
      #pragma unroll
      for (int c=0;c<10;c++) R[10+c]=(c==row)?1.0f:0.0f;
    }
    #pragma unroll
    for (int p=0;p<10;p++){
      float appv=__shfl(R[p],p);
      float ra=1.0f/appv;
      float fr=R[p];
      #pragma unroll
      for (int c=0;c<20;c++){
        float pc=__shfl(R[c],p)*ra;
        R[c]=(tid==p)? pc : fmaf(-fr,pc,R[c]);
      }
    }
    if (tid<10){
      float ht=0.f;
      #pragma unroll
      for (int c=0;c<10;c++){ s_Hi[tid*10+c]=R[10+c]; ht+=R[10+c]; }
      s_Ht[tid]=ht;
    }
  }
  __syncthreads();
  float dsum=0.f;
  #pragma unroll
  for (int k=0;k<10;k++) dsum+=s_Ht[k];
  const float rden=1.0f/dsum;
  if (tid<10) s_gv[tid]=s_Ht[tid]*rden;
  __syncthreads();
  if (tid<100){ int r=tid/10,c=tid-10*(tid/10); s_G[tid]=s_Hi[tid]-s_Ht[r]*s_Ht[c]*rden; }
  __syncthreads();
  if (tid<100){         // T = (C+I)G
    int r=tid/10,c=tid-10*(tid/10); float acc=0;
    #pragma unroll
    for (int j=0;j<10;j++) acc+=(s_C[r*10+j]+(r==j?1.0f:0.0f))*s_G[j*10+c];
    s_T[tid]=acc;
  }
  __syncthreads();
  if (tid<100){         // W = 4G(C+I)G - 4G ; emit G
    int r=tid/10,c=tid-10*(tid/10); float acc=0;
    #pragma unroll
    for (int j=0;j<10;j++) acc+=s_G[r*10+j]*s_T[j*10+c];
    ws[WS_SM+SM_W+tid]=4.0f*acc-4.0f*s_G[tid];
    ws[WS_SM+SM_G+tid]=s_G[tid];
  }
  if (tid<10){          // z = (C+I)g
    float acc=0;
    #pragma unroll
    for (int j=0;j<10;j++) acc+=(s_C[tid*10+j]+(tid==j?1.0f:0.0f))*s_gv[j];
    s_z[tid]=acc;
  }
  __syncthreads();
  if (tid<10){          // z2 = 2Gz - g
    float acc=0;
    #pragma unroll
    for (int j=0;j<10;j++) acc+=s_G[tid*10+j]*s_z[j];
    ws[WS_SM+SM_Z2+tid]=2.0f*acc-s_gv[tid];
  }
  if (tid==0){          // q00 = g^T C g + g.g
    float acc=0;
    #pragma unroll
    for (int r=0;r<10;r++){
      float rr=0;
      #pragma unroll
      for (int c=0;c<10;c++) rr+=s_C[r*10+c]*s_gv[c];
      acc+=s_gv[r]*rr+s_gv[r]*s_gv[r];
    }
    ws[WS_SM+SM_WSUM]=wsum; ws[WS_SM+SM_RWS]=rws; ws[WS_SM+SM_Q00]=acc; ws[WS_SM+3]=0.f;
  }
  // cT[c][l][u] = coef[l][4c+u] = s_mb[l*100+n]*s_sw[n]
  for (int i=tid;i<3000;i+=256){
    int l=i/100, n=i-100*l;
    ws[WS_CT + ((n>>2)*32 + l)*4 + (n&3)] = s_mb[i]*s_sw[n];
  }
  // zero pad lanes l=30,31
  for (int i=tid;i<200;i+=256){ int c=i>>3, r=i&7; ws[WS_CT+(c*32+30)*4+r]=0.f; }
  // wT (linear n)
  for (int i=tid;i<100;i+=256) ws[WS_WT+i]=s_w[i];
  if (tid<30){          // bs[l] = sum_n coef[l][n]
    const float4* p=(const float4*)&s_mb[tid*100];
    const float4* q=(const float4*)&s_sw[0];
    float acc=0;
    #pragma unroll 5
    for (int j=0;j<25;j++){ float4 x=p[j], yv=q[j];
      acc=fmaf(x.x,yv.x,acc); acc=fmaf(x.y,yv.y,acc);
      acc=fmaf(x.z,yv.z,acc); acc=fmaf(x.w,yv.w,acc); }
    ws[WS_SM+SM_BS+tid]=acc;
  }
  if (tid<10) ws[WS_SM+SM_GV+tid]=s_gv[tid];
  if (tid<30) ws[WS_SM+SM_BW+tid]=s_bw[tid];
}

// =================== kernel 2: 2048 blocks x 128 thr; 4 items/block, 32 lanes/item ===================
__global__ __launch_bounds__(128) void pace_main(const float* __restrict__ y,
                                                 const float* __restrict__ ws,
                                                 float* __restrict__ out){
  __shared__ __attribute__((aligned(16))) float S[LS_TOT];
  const int tid = threadIdx.x;
  // linear table stage (898 float4)
  for (int i=tid;i<898;i+=128) ((float4*)S)[i] = ((const float4*)ws)[i];
  __syncthreads();

  const int item = tid>>5, sub = tid&31;
  const int gb   = blockIdx.x*4 + item;
  const float* yb = y + gb*300;
  const float* smv = S + WS_SM;

  // ---- stats (n-split across 32 lanes) ----
  float swy0=0,swy1=0,swy2=0,s00=0,s01=0,s02=0,s11=0,s12=0,s22=0;
  #pragma unroll
  for (int m=0;m<3;m++){
    int n=sub+32*m;
    float y0=yb[n], y1=yb[100+n], y2=yb[200+n];
    float wn=S[WS_WT+n];
    float wy0=wn*y0,wy1=wn*y1,wy2=wn*y2;
    swy0+=wy0;swy1+=wy1;swy2+=wy2;
    s00+=wy0*y0;s01+=wy0*y1;s02+=wy0*y2;s11+=wy1*y1;s12+=wy1*y2;s22+=wy2*y2;
  }
  if (sub<4){
    int n=96+sub;
    float y0=yb[n], y1=yb[100+n], y2=yb[200+n];
    float wn=S[WS_WT+n];
    float wy0=wn*y0,wy1=wn*y1,wy2=wn*y2;
    swy0+=wy0;swy1+=wy1;swy2+=wy2;
    s00+=wy0*y0;s01+=wy0*y1;s02+=wy0*y2;s11+=wy1*y1;s12+=wy1*y2;s22+=wy2*y2;
  }
  swy0=gsum32(swy0); swy1=gsum32(swy1); swy2=gsum32(swy2);
  s00=gsum32(s00); s01=gsum32(s01); s02=gsum32(s02);
  s11=gsum32(s11); s12=gsum32(s12); s22=gsum32(s22);

  const float wsum=smv[SM_WSUM], rws=smv[SM_RWS];
  const float yw0=swy0*rws, yw1=swy1*rws, yw2=swy2*rws;

  // ---- F element-split: lane sub<30 owns coef row sub, 3 accumulators ----
  {
    float f0=0,f1=0,f2=0;
    if (sub<30){
      #pragma unroll 5
      for (int c=0;c<25;c++){
        float4 cf = *(const float4*)&S[WS_CT+(c*32+sub)*4];  // consecutive-lane b128
        float4 ya = *(const float4*)(yb+4*c);                // L1 broadcast
        float4 yB = *(const float4*)(yb+100+4*c);
        float4 yc = *(const float4*)(yb+200+4*c);
        f0=fmaf(cf.x,ya.x,f0); f0=fmaf(cf.y,ya.y,f0); f0=fmaf(cf.z,ya.z,f0); f0=fmaf(cf.w,ya.w,f0);
        f1=fmaf(cf.x,yB.x,f1); f1=fmaf(cf.y,yB.y,f1); f1=fmaf(cf.z,yB.z,f1); f1=fmaf(cf.w,yB.w,f1);
        f2=fmaf(cf.x,yc.x,f2); f2=fmaf(cf.y,yc.y,f2); f2=fmaf(cf.z,yc.z,f2); f2=fmaf(cf.w,yc.w,f2);
      }
      float bsv=smv[SM_BS+sub];
      f0-=yw0*bsv; f1-=yw1*bsv; f2-=yw2*bsv;
      S[LS_SF+item*96+sub*3+0]=f0;
      S[LS_SF+item*96+sub*3+1]=f1;
      S[LS_SF+item*96+sub*3+2]=f2;
    }
    if (sub==0){
      float* ax=S+LS_AX+item*16;
      ax[0]=yw0; ax[1]=yw1; ax[2]=yw2;
      ax[3+0]=s00-wsum*yw0*yw0;
      ax[3+4]=s11-wsum*yw1*yw1;
      ax[3+8]=s22-wsum*yw2*yw2;
      float g01=s01-wsum*yw0*yw1, g02=s02-wsum*yw0*yw2, g12=s12-wsum*yw1*yw2;
      ax[3+1]=g01; ax[3+3]=g01;
      ax[3+2]=g02; ax[3+6]=g02;
      ax[3+5]=g12; ax[3+7]=g12;
    }
  }
  __syncthreads();

  // ---- Q assembly: 36 column tasks + 4 q00 writes ----
  if (tid<36){
    int it2=tid/9, mp=tid-9*(tid/9);
    float fcol[10], t2[10];
    #pragma unroll
    for (int k=0;k<10;k++) fcol[k]=S[LS_SF+it2*96+k*9+mp];
    #pragma unroll
    for (int k=0;k<10;k++){
      float acc=0;
      #pragma unroll
      for (int k2=0;k2<10;k2++) acc+=smv[SM_W+k*10+k2]*fcol[k2];
      t2[k]=acc;
    }
    float he=0;
    #pragma unroll
    for (int k=0;k<10;k++) he+=smv[SM_Z2+k]*fcol[k];
    S[LS_QL+it2*57 + 1+mp]=he;
    #pragma unroll 1
    for (int m=0;m<=mp;m++){
      float gd=S[LS_AX+it2*16+3+(m%3)*3+(mp%3)];
      float acc=((m/3)==(mp/3))? gd : 0.f;
      #pragma unroll
      for (int k=0;k<10;k++) acc+=S[LS_SF+it2*96+k*9+m]*t2[k];
      int p=1+m, q=1+mp;
      S[LS_QL+it2*57 + p*10-((p*(p+1))>>1)+q]=acc;
    }
  }
  if (tid>=36 && tid<40) S[LS_QL+(tid-36)*57]=smv[SM_Q00];
  __syncthreads();

  // ================= Eigen + epilogue: one item per thread (tid<4) — R8-proven tail =================
  if (tid<4){
    const int it2=tid;
    const int gb2=blockIdx.x*4+it2;
    float A[55];
    #pragma unroll
    for (int e=0;e<55;e++) A[e]=S[LS_QL+it2*57+e];
    float dd[10], ee[9];
    #pragma unroll
    for (int k=0;k<8;k++){
      float nrm2=0.f;
      #pragma unroll
      for (int i=1;i<10;i++){ if (i<k+1) continue; float xi=A[SIDX(i,k)]; nrm2=fmaf(xi,xi,nrm2); }
      float x0=A[SIDX(k+1,k)];
      float nr=sqrtf(nrm2);
      float alpha=-copysignf(nr,x0);
      bool ok=nrm2>1e-30f;
      float v1=x0-alpha;
      float vtv=-2.0f*alpha*v1;
      float bh=ok?2.0f*__builtin_amdgcn_rcpf(vtv):0.f;
      ee[k]=ok?alpha:x0;
      float vv[10];
      #pragma unroll
      for (int i=0;i<10;i++) vv[i]=(i<k+1)?0.f:((i==k+1)?v1:A[SIDX(i,k)]);
      float p[10];
      #pragma unroll
      for (int i=0;i<10;i++){
        if (i<k+1){ p[i]=0.f; continue; }
        float acc=0;
        #pragma unroll
        for (int j=1;j<10;j++){ if (j<k+1) continue; acc+=A[SIDX(i,j)]*vv[j]; }
        p[i]=bh*acc;
      }
      float Kc=0.f;
      #pragma unroll
      for (int i=1;i<10;i++){ if (i<k+1) continue; Kc=fmaf(vv[i],p[i],Kc); }
      Kc*=0.5f*bh;
      float wv[10];
      #pragma unroll
      for (int i=0;i<10;i++) wv[i]=p[i]-Kc*vv[i];
      #pragma unroll
      for (int i=1;i<10;i++){
        if (i<k+1) continue;
        #pragma unroll
        for (int j=1;j<10;j++){
          if (j<i) continue;
          A[TRI(i,j)]-=vv[i]*wv[j]+wv[i]*vv[j];
        }
      }
    }
    ee[8]=A[TRI(8,9)];
    #pragma unroll
    for (int i=0;i<10;i++) dd[i]=A[TRI(i,i)];
    float esq[9];
    #pragma unroll
    for (int i=0;i<9;i++) esq[i]=ee[i]*ee[i];

    // Gershgorin bracket + serial bisection (16 iters)
    float scaleT=0.f, lo=1e30f, hi=1e30f;
    #pragma unroll
    for (int i=0;i<10;i++){
      float r=((i>0)?fabsf(ee[i-1]):0.f)+((i<9)?fabsf(ee[i]):0.f);
      scaleT=fmaxf(scaleT,fabsf(dd[i])+r);
      lo=fminf(lo,dd[i]-r);
      hi=fminf(hi,dd[i]);
    }
    hi+=1e-6f*scaleT+1e-30f;
    const float pm=1e-12f*scaleT+1e-37f;
    #pragma unroll 1
    for (int it=0;it<16;++it){
      float mid=0.5f*(lo+hi);
      float q=dd[0]-mid;
      q=(fabsf(q)<pm)?((q<0.f)?-pm:pm):q;
      int cnt=(q<0.f);
      #pragma unroll
      for (int i=1;i<10;i++){
        q=dd[i]-mid-esq[i-1]*__builtin_amdgcn_rcpf(q);
        q=(fabsf(q)<pm)?((q<0.f)?-pm:pm):q;
        cnt+=(q<0.f);
      }
      bool any=cnt>0;
      hi=any?mid:hi;
      lo=any?lo:mid;
    }
    const float sigma=lo-1e-5f*scaleT-1e-30f;   // cnt(sigma)==0; margin caps amplification
    const float pmL=1e-8f*scaleT+1e-37f;

    // dense Cholesky of (Q - sigma I) from LDS; overflow rails
    float Lc[55], rd[10];
    #pragma unroll
    for (int i=0;i<10;i++){
      #pragma unroll
      for (int j=0;j<10;j++){
        if (j>i) continue;
        float a=S[LS_QL+it2*57+SIDX(j,i)]-((i==j)?sigma:0.f);
        #pragma unroll
        for (int t2=0;t2<9;t2++){
          if (t2>=j) continue;
          a-=Lc[LTRI(i,t2)]*Lc[LTRI(j,t2)];
        }
        if (j<i) Lc[LTRI(i,j)]=a*rd[j];
        else { a=fmaxf(a,pmL); rd[i]=rsqrtf(a); Lc[LTRI(i,i)]=a*rd[i]; }
      }
    }
    float xv[10];
    #pragma unroll
    for (int i=0;i<10;i++) xv[i]=1.f;
    #pragma unroll 1
    for (int itr=0;itr<3;++itr){
      #pragma unroll
      for (int i=0;i<10;i++){
        float acc=xv[i];
        #pragma unroll
        for (int j=0;j<9;j++){ if (j>=i) continue; acc-=Lc[LTRI(i,j)]*xv[j]; }
        acc*=rd[i];
        xv[i]=fminf(fmaxf(acc,-1e15f),1e15f);
      }
      #pragma unroll
      for (int i=9;i>=0;i--){
        float acc=xv[i];
        #pragma unroll
        for (int j=9;j>0;j--){ if (j<=i) continue; acc-=Lc[LTRI(j,i)]*xv[j]; }
        acc*=rd[i];
        xv[i]=fminf(fmaxf(acc,-1e15f),1e15f);
      }
      float nn=0.f;
      #pragma unroll
      for (int i=0;i<10;i++) nn=fmaf(xv[i],xv[i],nn);
      nn=fmaxf(nn,1e-30f);
      float sc2=rsqrtf(nn);
      #pragma unroll
      for (int i=0;i<10;i++) xv[i]*=sc2;
    }
    float r0=1.0f/xv[0];
    float vn[10];
    vn[0]=1.f;
    #pragma unroll
    for (int m=1;m<10;m++) vn[m]=xv[m]*r0;

    // epilogue
    float dv[10];
    #pragma unroll
    for (int k=0;k<10;k++){
      float acc=0;
      #pragma unroll
      for (int m=0;m<9;m++) acc+=vn[1+m]*S[LS_SF+it2*96+k*9+m];
      dv[k]=acc;
    }
    float cv[10];
    #pragma unroll
    for (int k=0;k<10;k++){
      float acc=0;
      #pragma unroll
      for (int k2=0;k2<10;k2++) acc+=smv[SM_G+k*10+k2]*dv[k2];
      cv[k]=2.0f*acc+smv[SM_GV+k];
    }
    float e0=0,e1=0,e2=0;
    #pragma unroll
    for (int k=0;k<10;k++){
      e0+=smv[SM_BW+k*3+0]*cv[k];
      e1+=smv[SM_BW+k*3+1]*cv[k];
      e2+=smv[SM_BW+k*3+2]*cv[k];
    }
    float ywa=S[LS_AX+it2*16+0], ywb=S[LS_AX+it2*16+1], ywc=S[LS_AX+it2*16+2];
    #pragma unroll
    for (int i=0;i<3;i++)
      #pragma unroll
      for (int j=0;j<3;j++)
        out[gb2*9+i*3+j]=vn[1+3*j+i];
    out[73728+gb2*3+0]=ywa-(vn[1]*e0+vn[4]*e1+vn[7]*e2);
    out[73728+gb2*3+1]=ywb-(vn[2]*e0+vn[5]*e1+vn[8]*e2);
    out[73728+gb2*3+2]=ywc-(vn[3]*e0+vn[6]*e1+vn[9]*e2);
    #pragma unroll
    for (int k=0;k<10;k++)
      out[98304+gb2*10+k]=cv[k];
  }
}

extern "C" void kernel_launch(void* const* d_in, const int* in_sizes, int n_in,
                              void* d_out, int out_size, void* d_ws, size_t ws_size,
                              hipStream_t stream) {
  const float* y  = (const float*)d_in[0];   // (8192,3,100)
  const float* w  = (const float*)d_in[1];   // (100,1)
  const float* mk = (const float*)d_in[2];   // (10,3,100)
  float* out = (float*)d_out;                // R(8192*9) | t(8192*3) | c(8192*10)
  float* wsf = (float*)d_ws;
  pace_pre<<<1, 256, 0, stream>>>(w, mk, wsf);
  pace_main<<<2048, 128, 0, stream>>>(y, wsf, out);
}

// Round 10
// 101.152 us; speedup vs baseline: 1.2312x; 1.2312x over previous
//
#include <hip/hip_runtime.h>
#include <math.h>

// ---------------- persistent LDS layout (floats) ----------------
#define LT_CT 0        // cT[25][32][4]: cT[c][l][u] = coef[l][4c+u], rows 30/31 zero
#define LT_WT 3200     // w[100] + pad
#define LT_SM 3304     // sm[292]
#define LT_AR 3600     // union arena (7584 floats)
#define LT_TOT 11184   // 44736 B

#define SM_WSUM 0
#define SM_RWS  1
#define SM_Q00  2
#define SM_Z2   4
#define SM_BS   16     // 32 slots (30 used, 30/31 zeroed)
#define SM_W    48
#define SM_G    148
#define SM_GV   248
#define SM_BW   260

// arena phase-A offsets (relative to LT_AR)
#define A_YS 0         // [16][304]  staged y (stride 304 breaks mod-32)
#define A_SF 4864      // [16][97]   centered F (stride 97: conflict-free)
#define A_QL 6416      // [16][57]   Q upper-tri
#define A_AX 7328      // [16][16]   yw[3] @0, G3[9] @3

__host__ __device__ constexpr int TRI(int p,int q){ return p*10-(p*(p+1))/2+q; } // p<=q
__host__ __device__ constexpr int SIDX(int a,int b){ return (a<=b)?TRI(a,b):TRI(b,a); }
__host__ __device__ constexpr int LTRI(int i,int j){ return i*(i+1)/2+j; }       // j<=i

template<int CTRL>
__device__ __forceinline__ float dpp_add(float v){
  int s = __builtin_amdgcn_mov_dpp(__float_as_int(v), CTRL, 0xF, 0xF, true);
  return v + __int_as_float(s);
}
// 16-lane group sum (DPP row = 16 lanes)
__device__ __forceinline__ float gsum16(float v){
  v = dpp_add<0xB1>(v);    // quad xor1
  v = dpp_add<0x4E>(v);    // quad xor2
  v = dpp_add<0x141>(v);   // row_half_mirror
  v = dpp_add<0x140>(v);   // row_mirror
  return v;
}

__global__ __launch_bounds__(256,2) void pace_fused(const float* __restrict__ y,
                                                    const float* __restrict__ w,
                                                    const float* __restrict__ mk,
                                                    float* __restrict__ out){
  __shared__ __attribute__((aligned(16))) float S[LT_TOT];
  const int tid  = threadIdx.x;
  const int lane = tid & 63;
  const int sub  = tid & 15;      // lane within item
  const int item = tid >> 4;      // 0..15

  // ================= Phase P: per-block precompute (identical across blocks) =================
  {
    float* s_mb = S+LT_AR;        // 3000: mk staged, then bar_b in place
    float* s_w  = S+LT_AR+3000;
    float* s_sw = S+LT_AR+3104;
    float* s_bw = S+LT_AR+3208;
    float* s_C  = S+LT_AR+3240;
    float* s_Hi = S+LT_AR+3340;
    float* s_G  = S+LT_AR+3440;
    float* s_T  = S+LT_AR+3540;
    float* s_gv = S+LT_AR+3640;
    float* s_Ht = S+LT_AR+3652;
    float* s_z  = S+LT_AR+3664;
    float* sm   = S+LT_SM;

    for (int i=tid;i<3000;i+=256) s_mb[i]=mk[i];
    for (int i=tid;i<100;i+=256){ float x=w[i]; s_w[i]=x; s_sw[i]=sqrtf(x); }
    __syncthreads();

    float av = s_w[lane] + ((lane<36)? s_w[lane+64] : 0.f);
    #pragma unroll
    for (int m=32;m;m>>=1) av += __shfl_xor(av,m);
    const float wsum = av;
    const float rws  = 1.0f/av;

    if (tid<30){      // b_w rows
      const float4* p=(const float4*)&s_mb[tid*100];
      const float4* q=(const float4*)&s_w[0];
      float acc=0;
      #pragma unroll 5
      for (int j=0;j<25;j++){ float4 x=p[j], yv=q[j];
        acc=fmaf(x.x,yv.x,acc); acc=fmaf(x.y,yv.y,acc);
        acc=fmaf(x.z,yv.z,acc); acc=fmaf(x.w,yv.w,acc); }
      s_bw[tid]=acc*rws;
    }
    __syncthreads();
    for (int i=tid;i<3000;i+=256){ int r=i/100, n=i-r*100; s_mb[i]=s_sw[n]*(s_mb[i]-s_bw[r]); }
    __syncthreads();
    if (tid<100){     // C = barB^T barB
      int k=tid/10, k2=tid-10*(tid/10);
      const float4* p1=(const float4*)&s_mb[k*300];
      const float4* p2=(const float4*)&s_mb[k2*300];
      float acc=0;
      #pragma unroll 5
      for (int j=0;j<75;j++){ float4 x=p1[j], yv=p2[j];
        acc=fmaf(x.x,yv.x,acc); acc=fmaf(x.y,yv.y,acc);
        acc=fmaf(x.z,yv.z,acc); acc=fmaf(x.w,yv.w,acc); }
      s_C[tid]=acc;
    }
    __syncthreads();
    if (tid<64){      // GJ inversion of 2(C+I), wave0 lanes 0..9 own rows
      float R[20];
      {
        int row=(tid<10)? tid : 0;
        #pragma unroll
        for (int c=0;c<10;c++) R[c]=2.0f*(s_C[row*10+c]+(c==row?1.0f:0.0f));
        #pragma unroll
        for (int c=0;c<10;c++) R[10+c]=(c==row)?1.0f:0.0f;
      }
      #pragma unroll
      for (int p=0;p<10;p++){
        float appv=__shfl(R[p],p);
        float ra=1.0f/appv;
        float fr=R[p];
        #pragma unroll
        for (int c=0;c<20;c++){
          float pc=__shfl(R[c],p)*ra;
          R[c]=(tid==p)? pc : fmaf(-fr,pc,R[c]);
        }
      }
      if (tid<10){
        float ht=0.f;
        #pragma unroll
        for (int c=0;c<10;c++){ s_Hi[tid*10+c]=R[10+c]; ht+=R[10+c]; }
        s_Ht[tid]=ht;
      }
    }
    __syncthreads();
    float dsum=0.f;
    #pragma unroll
    for (int k=0;k<10;k++) dsum+=s_Ht[k];
    const float rden=1.0f/dsum;
    if (tid<10) s_gv[tid]=s_Ht[tid]*rden;
    __syncthreads();
    if (tid<100){ int r=tid/10,c=tid-10*(tid/10); s_G[tid]=s_Hi[tid]-s_Ht[r]*s_Ht[c]*rden; }
    __syncthreads();
    if (tid<100){     // T = (C+I)G
      int r=tid/10,c=tid-10*(tid/10); float acc=0;
      #pragma unroll
      for (int j=0;j<10;j++) acc+=(s_C[r*10+j]+(r==j?1.0f:0.0f))*s_G[j*10+c];
      s_T[tid]=acc;
    }
    __syncthreads();
    if (tid<100){     // W = 4G(C+I)G - 4G ; emit G
      int r=tid/10,c=tid-10*(tid/10); float acc=0;
      #pragma unroll
      for (int j=0;j<10;j++) acc+=s_G[r*10+j]*s_T[j*10+c];
      sm[SM_W+tid]=4.0f*acc-4.0f*s_G[tid];
      sm[SM_G+tid]=s_G[tid];
    }
    if (tid<10){      // z = (C+I)g
      float acc=0;
      #pragma unroll
      for (int j=0;j<10;j++) acc+=(s_C[tid*10+j]+(tid==j?1.0f:0.0f))*s_gv[j];
      s_z[tid]=acc;
    }
    __syncthreads();
    if (tid<10){      // z2 = 2Gz - g
      float acc=0;
      #pragma unroll
      for (int j=0;j<10;j++) acc+=s_G[tid*10+j]*s_z[j];
      sm[SM_Z2+tid]=2.0f*acc-s_gv[tid];
    }
    if (tid==0){      // q00 = g^T C g + g.g
      float acc=0;
      #pragma unroll
      for (int r=0;r<10;r++){
        float rr=0;
        #pragma unroll
        for (int c=0;c<10;c++) rr+=s_C[r*10+c]*s_gv[c];
        acc+=s_gv[r]*rr+s_gv[r]*s_gv[r];
      }
      sm[SM_WSUM]=wsum; sm[SM_RWS]=rws; sm[SM_Q00]=acc; sm[3]=0.f;
    }
    // cT[c][l][u] = barb[l][n]*sw[n], n=4c+u  (transposed for consecutive-lane b128)
    for (int i=tid;i<3000;i+=256){
      int l=i/100, n=i-100*l;
      S[LT_CT + ((n>>2)*32 + l)*4 + (n&3)] = s_mb[i]*s_sw[n];
    }
    for (int i=tid;i<200;i+=256){ int c=i>>3, r=i&7; S[LT_CT+(c*32+30)*4+r]=0.f; } // rows 30,31
    for (int i=tid;i<100;i+=256) S[LT_WT+i]=s_w[i];
    if (tid<30){      // bs[row] = sum_n barb*sw
      const float4* p=(const float4*)&s_mb[tid*100];
      const float4* q=(const float4*)&s_sw[0];
      float acc=0;
      #pragma unroll 5
      for (int j=0;j<25;j++){ float4 x=p[j], yv=q[j];
        acc=fmaf(x.x,yv.x,acc); acc=fmaf(x.y,yv.y,acc);
        acc=fmaf(x.z,yv.z,acc); acc=fmaf(x.w,yv.w,acc); }
      sm[SM_BS+tid]=acc;
    }
    if (tid<2)  sm[SM_BS+30+tid]=0.f;       // pad rows
    if (tid<10) sm[SM_GV+tid]=s_gv[tid];
    if (tid<30) sm[SM_BW+tid]=s_bw[tid];
    __syncthreads();   // Phase P done; arena reusable
  }

  const float* sm = S+LT_SM;
  float* yS = S+LT_AR+A_YS;
  float* sF = S+LT_AR+A_SF;
  float* sQ = S+LT_AR+A_QL;
  float* sX = S+LT_AR+A_AX;

  // ---- A1: stage this block's 16 y items into LDS (coalesced linear f4 copy) ----
  {
    const float4* yg = (const float4*)(y + (size_t)blockIdx.x*4800);
    #pragma unroll
    for (int r=0;r<5;r++){
      int f = tid + 256*r;
      if (f<1200){
        int it2=f/75, rem=f-75*it2;
        ((float4*)&yS[it2*304])[rem] = yg[f];
      }
    }
  }
  __syncthreads();

  const float* yb = &yS[item*304];

  // ---- A2: stats (n-split over the item's 16 lanes) ----
  float swy0=0,swy1=0,swy2=0,s00=0,s01=0,s02=0,s11=0,s12=0,s22=0;
  #pragma unroll
  for (int m=0;m<6;m++){
    int n=sub+16*m;
    float y0=yb[n], y1=yb[100+n], y2=yb[200+n];
    float wn=S[LT_WT+n];
    float wy0=wn*y0,wy1=wn*y1,wy2=wn*y2;
    swy0+=wy0;swy1+=wy1;swy2+=wy2;
    s00+=wy0*y0;s01+=wy0*y1;s02+=wy0*y2;s11+=wy1*y1;s12+=wy1*y2;s22+=wy2*y2;
  }
  if (sub<4){
    int n=96+sub;
    float y0=yb[n], y1=yb[100+n], y2=yb[200+n];
    float wn=S[LT_WT+n];
    float wy0=wn*y0,wy1=wn*y1,wy2=wn*y2;
    swy0+=wy0;swy1+=wy1;swy2+=wy2;
    s00+=wy0*y0;s01+=wy0*y1;s02+=wy0*y2;s11+=wy1*y1;s12+=wy1*y2;s22+=wy2*y2;
  }
  swy0=gsum16(swy0); swy1=gsum16(swy1); swy2=gsum16(swy2);
  s00=gsum16(s00); s01=gsum16(s01); s02=gsum16(s02);
  s11=gsum16(s11); s12=gsum16(s12); s22=gsum16(s22);

  const float wsum=sm[SM_WSUM], rws=sm[SM_RWS];
  const float yw0=swy0*rws, yw1=swy1*rws, yw2=swy2*rws;

  // ---- A3: F element-split — lane owns coef rows sub and sub+16 (6 scalar accs) ----
  {
    float a0=0,a1=0,a2=0,b0=0,b1=0,b2=0;
    #pragma unroll 5
    for (int c=0;c<25;c++){
      float4 cfA = *(const float4*)&S[LT_CT+(c*32+sub)*4];
      float4 cfB = *(const float4*)&S[LT_CT+(c*32+sub+16)*4];
      float4 ya  = *(const float4*)&yb[4*c];
      float4 yB  = *(const float4*)&yb[100+4*c];
      float4 yc  = *(const float4*)&yb[200+4*c];
      a0=fmaf(cfA.x,ya.x,a0); a0=fmaf(cfA.y,ya.y,a0); a0=fmaf(cfA.z,ya.z,a0); a0=fmaf(cfA.w,ya.w,a0);
      a1=fmaf(cfA.x,yB.x,a1); a1=fmaf(cfA.y,yB.y,a1); a1=fmaf(cfA.z,yB.z,a1); a1=fmaf(cfA.w,yB.w,a1);
      a2=fmaf(cfA.x,yc.x,a2); a2=fmaf(cfA.y,yc.y,a2); a2=fmaf(cfA.z,yc.z,a2); a2=fmaf(cfA.w,yc.w,a2);
      b0=fmaf(cfB.x,ya.x,b0); b0=fmaf(cfB.y,ya.y,b0); b0=fmaf(cfB.z,ya.z,b0); b0=fmaf(cfB.w,ya.w,b0);
      b1=fmaf(cfB.x,yB.x,b1); b1=fmaf(cfB.y,yB.y,b1); b1=fmaf(cfB.z,yB.z,b1); b1=fmaf(cfB.w,yB.w,b1);
      b2=fmaf(cfB.x,yc.x,b2); b2=fmaf(cfB.y,yc.y,b2); b2=fmaf(cfB.z,yc.z,b2); b2=fmaf(cfB.w,yc.w,b2);
    }
    float bsA=sm[SM_BS+sub], bsB=sm[SM_BS+sub+16];
    a0-=yw0*bsA; a1-=yw1*bsA; a2-=yw2*bsA;
    b0-=yw0*bsB; b1-=yw1*bsB; b2-=yw2*bsB;
    sF[item*97+sub*3+0]=a0; sF[item*97+sub*3+1]=a1; sF[item*97+sub*3+2]=a2;
    sF[item*97+48+sub*3+0]=b0; sF[item*97+48+sub*3+1]=b1; sF[item*97+48+sub*3+2]=b2;
    if (sub==0){
      float* ax=&sX[item*16];
      ax[0]=yw0; ax[1]=yw1; ax[2]=yw2;
      ax[3+0]=s00-wsum*yw0*yw0;
      ax[3+4]=s11-wsum*yw1*yw1;
      ax[3+8]=s22-wsum*yw2*yw2;
      float g01=s01-wsum*yw0*yw1, g02=s02-wsum*yw0*yw2, g12=s12-wsum*yw1*yw2;
      ax[3+1]=g01; ax[3+3]=g01;
      ax[3+2]=g02; ax[3+6]=g02;
      ax[3+5]=g12; ax[3+7]=g12;
    }
  }
  __syncthreads();

  // ---- A4: Q assembly — 144 column tasks + 16 q00 writes ----
  if (tid<144){
    int it2=tid/9, mp=tid-9*(tid/9);
    float fcol[10], t2[10];
    #pragma unroll
    for (int k=0;k<10;k++) fcol[k]=sF[it2*97+k*9+mp];
    #pragma unroll
    for (int k=0;k<10;k++){
      float acc=0;
      #pragma unroll
      for (int k2=0;k2<10;k2++) acc+=sm[SM_W+k*10+k2]*fcol[k2];
      t2[k]=acc;
    }
    float he=0;
    #pragma unroll
    for (int k=0;k<10;k++) he+=sm[SM_Z2+k]*fcol[k];
    sQ[it2*57 + 1+mp]=he;
    #pragma unroll 1
    for (int m=0;m<=mp;m++){
      float gd=sX[it2*16+3+(m%3)*3+(mp%3)];
      float acc=((m/3)==(mp/3))? gd : 0.f;
      #pragma unroll
      for (int k=0;k<10;k++) acc+=sF[it2*97+k*9+m]*t2[k];
      int p=1+m, q=1+mp;
      sQ[it2*57 + p*10-((p*(p+1))>>1)+q]=acc;
    }
  }
  if (tid>=144 && tid<160) sQ[(tid-144)*57]=sm[SM_Q00];
  __syncthreads();

  // ================= Eigen + epilogue: one item per lane (tid<16) — R8-proven tail =================
  if (tid<16){
    const int it2=tid;
    const int gb2=blockIdx.x*16+it2;
    float A[55];
    #pragma unroll
    for (int e=0;e<55;e++) A[e]=sQ[it2*57+e];
    float dd[10], ee[9];
    #pragma unroll
    for (int k=0;k<8;k++){
      float nrm2=0.f;
      #pragma unroll
      for (int i=1;i<10;i++){ if (i<k+1) continue; float xi=A[SIDX(i,k)]; nrm2=fmaf(xi,xi,nrm2); }
      float x0=A[SIDX(k+1,k)];
      float nr=sqrtf(nrm2);
      float alpha=-copysignf(nr,x0);
      bool ok=nrm2>1e-30f;
      float v1=x0-alpha;
      float vtv=-2.0f*alpha*v1;
      float bh=ok?2.0f*__builtin_amdgcn_rcpf(vtv):0.f;
      ee[k]=ok?alpha:x0;
      float vv[10];
      #pragma unroll
      for (int i=0;i<10;i++) vv[i]=(i<k+1)?0.f:((i==k+1)?v1:A[SIDX(i,k)]);
      float p[10];
      #pragma unroll
      for (int i=0;i<10;i++){
        if (i<k+1){ p[i]=0.f; continue; }
        float acc=0;
        #pragma unroll
        for (int j=1;j<10;j++){ if (j<k+1) continue; acc+=A[SIDX(i,j)]*vv[j]; }
        p[i]=bh*acc;
      }
      float Kc=0.f;
      #pragma unroll
      for (int i=1;i<10;i++){ if (i<k+1) continue; Kc=fmaf(vv[i],p[i],Kc); }
      Kc*=0.5f*bh;
      float wv[10];
      #pragma unroll
      for (int i=0;i<10;i++) wv[i]=p[i]-Kc*vv[i];
      #pragma unroll
      for (int i=1;i<10;i++){
        if (i<k+1) continue;
        #pragma unroll
        for (int j=1;j<10;j++){
          if (j<i) continue;
          A[TRI(i,j)]-=vv[i]*wv[j]+wv[i]*vv[j];
        }
      }
    }
    ee[8]=A[TRI(8,9)];
    #pragma unroll
    for (int i=0;i<10;i++) dd[i]=A[TRI(i,i)];
    float esq[9];
    #pragma unroll
    for (int i=0;i<9;i++) esq[i]=ee[i]*ee[i];

    float scaleT=0.f, lo=1e30f, hi=1e30f;
    #pragma unroll
    for (int i=0;i<10;i++){
      float r=((i>0)?fabsf(ee[i-1]):0.f)+((i<9)?fabsf(ee[i]):0.f);
      scaleT=fmaxf(scaleT,fabsf(dd[i])+r);
      lo=fminf(lo,dd[i]-r);
      hi=fminf(hi,dd[i]);
    }
    hi+=1e-6f*scaleT+1e-30f;
    const float pm=1e-12f*scaleT+1e-37f;
    #pragma unroll 1
    for (int it=0;it<16;++it){
      float mid=0.5f*(lo+hi);
      float q=dd[0]-mid;
      q=(fabsf(q)<pm)?((q<0.f)?-pm:pm):q;
      int cnt=(q<0.f);
      #pragma unroll
      for (int i=1;i<10;i++){
        q=dd[i]-mid-esq[i-1]*__builtin_amdgcn_rcpf(q);
        q=(fabsf(q)<pm)?((q<0.f)?-pm:pm):q;
        cnt+=(q<0.f);
      }
      bool any=cnt>0;
      hi=any?mid:hi;
      lo=any?lo:mid;
    }
    const float sigma=lo-1e-5f*scaleT-1e-30f;   // cnt(sigma)==0; margin caps amplification
    const float pmL=1e-8f*scaleT+1e-37f;

    float Lc[55], rd[10];
    #pragma unroll
    for (int i=0;i<10;i++){
      #pragma unroll
      for (int j=0;j<10;j++){
        if (j>i) continue;
        float a=sQ[it2*57+SIDX(j,i)]-((i==j)?sigma:0.f);
        #pragma unroll
        for (int t2=0;t2<9;t2++){
          if (t2>=j) continue;
          a-=Lc[LTRI(i,t2)]*Lc[LTRI(j,t2)];
        }
        if (j<i) Lc[LTRI(i,j)]=a*rd[j];
        else { a=fmaxf(a,pmL); rd[i]=rsqrtf(a); Lc[LTRI(i,i)]=a*rd[i]; }
      }
    }
    float xv[10];
    #pragma unroll
    for (int i=0;i<10;i++) xv[i]=1.f;
    #pragma unroll 1
    for (int itr=0;itr<3;++itr){
      #pragma unroll
      for (int i=0;i<10;i++){
        float acc=xv[i];
        #pragma unroll
        for (int j=0;j<9;j++){ if (j>=i) continue; acc-=Lc[LTRI(i,j)]*xv[j]; }
        acc*=rd[i];
        xv[i]=fminf(fmaxf(acc,-1e15f),1e15f);
      }
      #pragma unroll
      for (int i=9;i>=0;i--){
        float acc=xv[i];
        #pragma unroll
        for (int j=9;j>0;j--){ if (j<=i) continue; acc-=Lc[LTRI(j,i)]*xv[j]; }
        acc*=rd[i];
        xv[i]=fminf(fmaxf(acc,-1e15f),1e15f);
      }
      float nn=0.f;
      #pragma unroll
      for (int i=0;i<10;i++) nn=fmaf(xv[i],xv[i],nn);
      nn=fmaxf(nn,1e-30f);
      float sc2=rsqrtf(nn);
      #pragma unroll
      for (int i=0;i<10;i++) xv[i]*=sc2;
    }
    float r0=1.0f/xv[0];
    float vn[10];
    vn[0]=1.f;
    #pragma unroll
    for (int m=1;m<10;m++) vn[m]=xv[m]*r0;

    // epilogue
    float dv[10];
    #pragma unroll
    for (int k=0;k<10;k++){
      float acc=0;
      #pragma unroll
      for (int m=0;m<9;m++) acc+=vn[1+m]*sF[it2*97+k*9+m];
      dv[k]=acc;
    }
    float cv[10];
    #pragma unroll
    for (int k=0;k<10;k++){
      float acc=0;
      #pragma unroll
      for (int k2=0;k2<10;k2++) acc+=sm[SM_G+k*10+k2]*dv[k2];
      cv[k]=2.0f*acc+sm[SM_GV+k];
    }
    float e0=0,e1=0,e2=0;
    #pragma unroll
    for (int k=0;k<10;k++){
      e0+=sm[SM_BW+k*3+0]*cv[k];
      e1+=sm[SM_BW+k*3+1]*cv[k];
      e2+=sm[SM_BW+k*3+2]*cv[k];
    }
    float ywa=sX[it2*16+0], ywb=sX[it2*16+1], ywc=sX[it2*16+2];
    #pragma unroll
    for (int i=0;i<3;i++)
      #pragma unroll
      for (int j=0;j<3;j++)
        out[gb2*9+i*3+j]=vn[1+3*j+i];
    out[73728+gb2*3+0]=ywa-(vn[1]*e0+vn[4]*e1+vn[7]*e2);
    out[73728+gb2*3+1]=ywb-(vn[2]*e0+vn[5]*e1+vn[8]*e2);
    out[73728+gb2*3+2]=ywc-(vn[3]*e0+vn[6]*e1+vn[9]*e2);
    #pragma unroll
    for (int k=0;k<10;k++)
      out[98304+gb2*10+k]=cv[k];
  }
}

extern "C" void kernel_launch(void* const* d_in, const int* in_sizes, int n_in,
                              void* d_out, int out_size, void* d_ws, size_t ws_size,
                              hipStream_t stream) {
  const float* y  = (const float*)d_in[0];   // (8192,3,100)
  const float* w  = (const float*)d_in[1];   // (100,1)
  const float* mk = (const float*)d_in[2];   // (10,3,100)
  float* out = (float*)d_out;                // R(8192*9) | t(8192*3) | c(8192*10)
  pace_fused<<<512, 256, 0, stream>>>(y, w, mk, out);
}